// Round 5
// baseline (7230.769 us; speedup 1.0000x reference)
//
#include <hip/hip_runtime.h>

typedef unsigned int uint32;

#define GBLK 256
#define BT 512
#define NSTEP 128

// ---- workspace layout ----
// Per-block flag words (ints): flags[c*256 + b] = step tag published by block b.
// Plain relaxed agent stores (NO atomic RMW -> no hot-line serialization).
#define CQ   0   // slots 128..255 only (upper blocks produce q)
#define CGH  1
#define CE   2
#define CCTX 3
#define CH1  4
#define CH2  5
// float data (untagged fp32), float indices:
#define QF    2048
#define EF    3072
#define CTXF  3328
#define H1FO  5376
#define H2FO  6400
#define O1F   7424
#define O2F   8448
#define GH1F  9472
#define GH2F  13568
// end 17664 floats = 70.7 KB

struct Params {
  const int* inputs;
  const float *h1_in, *h2_in, *embeds, *vatt;
  const float *pk, *enc, *Wq, *Wih1, *Whh1, *Wih2, *Whh2, *Wpre, *Wout;
  const float *bih1, *bhh1, *bih2, *bhh2, *bpre, *bout;
  float* out;
  float* ws;
};

__device__ __forceinline__ float blo(uint32 u) { return __uint_as_float(u << 16); }
__device__ __forceinline__ float bhi(uint32 u) { return __uint_as_float(u & 0xffff0000u); }
__device__ __forceinline__ uint32 bfr(float f) {  // fp32 -> bf16 bits, RNE
  uint32 u = __float_as_uint(f);
  return (u + 0x7fffu + ((u >> 16) & 1u)) >> 16;
}

// agent-scope (MALL-coherent) scalar access
__device__ __forceinline__ float ald(const float* a) {
  return __hip_atomic_load(a, __ATOMIC_RELAXED, __HIP_MEMORY_SCOPE_AGENT);
}
__device__ __forceinline__ void ast(float* a, float v) {
  __hip_atomic_store(a, v, __ATOMIC_RELAXED, __HIP_MEMORY_SCOPE_AGENT);
}
__device__ __forceinline__ int aldi(const int* a) {
  return __hip_atomic_load(a, __ATOMIC_RELAXED, __HIP_MEMORY_SCOPE_AGENT);
}
__device__ __forceinline__ void asti(int* a, int v) {
  __hip_atomic_store(a, v, __ATOMIC_RELAXED, __HIP_MEMORY_SCOPE_AGENT);
}

// 16B device-coherent loads (bypass L1/L2 -> MALL)
__device__ __forceinline__ float4 cld16(const float* p) {
  float4 r;
  asm volatile("global_load_dwordx4 %0, %1, off sc0 sc1\n\ts_waitcnt vmcnt(0)"
               : "=&v"(r) : "v"(p) : "memory");
  return r;
}
__device__ __forceinline__ int4 cldi4(const int* p) {
  int4 r;
  asm volatile("global_load_dwordx4 %0, %1, off sc0 sc1\n\ts_waitcnt vmcnt(0)"
               : "=&v"(r) : "v"(p) : "memory");
  return r;
}

// drain this wave's outstanding stores (manual release, no wbL2)
#define VDRAIN() asm volatile("s_waitcnt vmcnt(0)" ::: "memory")

// ---- flag rendezvous: per-block store + wave-0 parallel poll ----
__device__ __forceinline__ void fst(int* flg, int c, int slot, int v) {
  asti(flg + c * 256 + slot, v);
}
// wave0: all 256 slots of region c >= tgt (64 lanes x int4)
__device__ __forceinline__ void fpoll256(const int* flg, int c, int tgt, int lane) {
  const int* base = flg + c * 256 + lane * 4;
  for (;;) {
    int4 v = cldi4(base);
    bool ok = v.x >= tgt && v.y >= tgt && v.z >= tgt && v.w >= tgt;
    if (__all(ok)) return;
    __builtin_amdgcn_s_sleep(1);
  }
}
// wave0: regions c1 AND c2, all 256 slots each
__device__ __forceinline__ void fpoll2x256(const int* flg, int c1, int c2, int tgt, int lane) {
  const int* b1 = flg + c1 * 256 + lane * 4;
  const int* b2 = flg + c2 * 256 + lane * 4;
  for (;;) {
    int4 v, u;
    asm volatile("global_load_dwordx4 %0, %2, off sc0 sc1\n\t"
                 "global_load_dwordx4 %1, %3, off sc0 sc1\n\t"
                 "s_waitcnt vmcnt(0)"
                 : "=&v"(v), "=&v"(u) : "v"(b1), "v"(b2) : "memory");
    bool ok = v.x >= tgt && v.y >= tgt && v.z >= tgt && v.w >= tgt &&
              u.x >= tgt && u.y >= tgt && u.z >= tgt && u.w >= tgt;
    if (__all(ok)) return;
    __builtin_amdgcn_s_sleep(1);
  }
}
// wave0: slots 128..255 of region c (lanes 0..31 cover, others duplicate)
__device__ __forceinline__ void fpoll128hi(const int* flg, int c, int tgt, int lane) {
  const int* base = flg + c * 256 + 128 + (lane & 31) * 4;
  for (;;) {
    int4 v = cldi4(base);
    bool ok = v.x >= tgt && v.y >= tgt && v.z >= tgt && v.w >= tgt;
    if (__all(ok)) return;
    __builtin_amdgcn_s_sleep(1);
  }
}
// all lanes of wave0: two specific slots (point-to-point gh dependency)
__device__ __forceinline__ void fpollp2(const int* flg, int c, int s0, int s1, int tgt) {
  const int* a0 = flg + c * 256 + s0;
  const int* a1 = flg + c * 256 + s1;
  for (;;) {
    if (aldi(a0) >= tgt && aldi(a1) >= tgt) return;
    __builtin_amdgcn_s_sleep(1);
  }
}

__device__ __forceinline__ float wsum(float v) {
#pragma unroll
  for (int o = 32; o; o >>= 1) v += __shfl_xor(v, o, 64);
  return v;
}

// one-time fp32->bf16x2 packed weight chunk load (stays in VGPRs all 128 steps)
__device__ __forceinline__ void ldchunk(const float* W, size_t base, int lane, uint32* r) {
  const float* wf = W + base + lane * 8;
  float4 a = *(const float4*)wf;
  float4 c = *(const float4*)(wf + 4);
  r[0] = bfr(a.x) | (bfr(a.y) << 16);
  r[1] = bfr(a.z) | (bfr(a.w) << 16);
  r[2] = bfr(c.x) | (bfr(c.y) << 16);
  r[3] = bfr(c.z) | (bfr(c.w) << 16);
}

__device__ __forceinline__ float dotchunk(const uint32* r, const float* xc, int lane) {
  const float* x = xc + lane * 8;
  float4 x0 = *(const float4*)x, x1 = *(const float4*)(x + 4);
  return blo(r[0]) * x0.x + bhi(r[0]) * x0.y + blo(r[1]) * x0.z + bhi(r[1]) * x0.w +
         blo(r[2]) * x1.x + bhi(r[2]) * x1.y + blo(r[3]) * x1.z + bhi(r[3]) * x1.w;
}

__device__ __forceinline__ float sigm(float x) { return 1.f / (1.f + expf(-x)); }
__device__ __forceinline__ float lrelu(float x) { return x >= 0.f ? x : 0.01f * x; }

__global__ __launch_bounds__(BT, 2) void dec_flag_kernel(Params p) {
  // sx: [0:512) emb | [512:2560) ctx | [2560:3584) o2/o1 | [4096:4352) e |
  //     [6144:7168) h1 | [7168:8192) h2
  __shared__ float sx[8192];
  __shared__ float s_red[8];
  __shared__ float s_part[72];

  const int tid = threadIdx.x;
  const int lane = tid & 63;
  const int w = tid >> 6;
  const int b = blockIdx.x;
  const int gw = b * 8 + w;          // 0..2047
  const int i0 = b * 4;
  const int j0 = b * 8;

  int* flg = (int*)p.ws;

  float* outs = p.out;            // 128*512
  float* pres = p.out + 65536;    // 128*1024
  float* alph = p.out + 196608;   // 128*256
  float* h1f = p.out + 229376;
  float* h2f = p.out + 230400;

  // ======== Register-resident weights (once) ========
  uint32 wa[48];
  if (gw < 1024) {
#pragma unroll
    for (int c = 0; c < 7; ++c)
      ldchunk(p.Wpre, (size_t)gw * 3584 + c * 512, lane, wa + 4 * c);
    ldchunk(p.Whh1, (size_t)gw * 1024, lane, wa + 28);
    ldchunk(p.Whh1, (size_t)gw * 1024 + 512, lane, wa + 32);
    ldchunk(p.Whh1, (size_t)(gw + 1024) * 1024, lane, wa + 36);
    ldchunk(p.Whh1, (size_t)(gw + 1024) * 1024 + 512, lane, wa + 40);
    wa[44] = wa[45] = wa[46] = wa[47] = 0u;
  } else {
    const int widx = gw - 1024;
    ldchunk(p.Whh1, (size_t)(2048 + widx) * 1024, lane, wa + 0);
    ldchunk(p.Whh1, (size_t)(2048 + widx) * 1024 + 512, lane, wa + 4);
#pragma unroll
    for (int r = 0; r < 3; ++r) {
      ldchunk(p.Whh2, (size_t)(widx + r * 1024) * 1024, lane, wa + 8 + 8 * r);
      ldchunk(p.Whh2, (size_t)(widx + r * 1024) * 1024 + 512, lane, wa + 12 + 8 * r);
    }
    ldchunk(p.Wq, (size_t)widx * 1024, lane, wa + 32);
    ldchunk(p.Wq, (size_t)widx * 1024 + 512, lane, wa + 36);
    const int wr = widx & 511;  // clamp; store guarded by widx<512
    ldchunk(p.Wout, (size_t)wr * 1024, lane, wa + 40);
    ldchunk(p.Wout, (size_t)wr * 1024 + 512, lane, wa + 44);
  }

  uint32 wd[32];
#pragma unroll
  for (int k = 0; k < 8; ++k) {
    const int mm = w + 8 * k;
    const int mmc = mm < 60 ? mm : 0;
    const int r = mmc / 15, m = mmc % 15, g = m / 5, c = m % 5;
    ldchunk(p.Wih1, (size_t)(g * 1024 + i0 + r) * 2560 + c * 512, lane, wd + 4 * k);
  }

  uint32 we9[36];
#pragma unroll
  for (int k = 0; k < 9; ++k) {
    const int mm = w + 8 * k;
    const int r = mm / 18, m = mm % 18, g = m / 6, c = m % 6;
    ldchunk(p.Wih2, (size_t)(g * 1024 + i0 + r) * 3072 + c * 512, lane, we9 + 4 * k);
  }

  uint32 wenc[4] = {0u, 0u, 0u, 0u};
  float4 pk4 = {0.f, 0.f, 0.f, 0.f}, va4 = {0.f, 0.f, 0.f, 0.f};
  if (tid < 256) {
    const float* er = p.enc + (size_t)tid * 2048 + j0;
    float4 a = *(const float4*)er, c = *(const float4*)(er + 4);
    wenc[0] = bfr(a.x) | (bfr(a.y) << 16);
    wenc[1] = bfr(a.z) | (bfr(a.w) << 16);
    wenc[2] = bfr(c.x) | (bfr(c.y) << 16);
    wenc[3] = bfr(c.z) | (bfr(c.w) << 16);
    pk4 = *(const float4*)(p.pk + (size_t)b * 1024 + 4 * tid);
    va4 = *(const float4*)(p.vatt + 4 * tid);
  }

  // ======== init recurrent state: block owns rows i0..i0+3 ========
  if (tid < 4) {
    ast(p.ws + H1FO + i0 + tid, p.h1_in[i0 + tid]);
    ast(p.ws + H2FO + i0 + tid, p.h2_in[i0 + tid]);
  }
  VDRAIN();  // stores were in wave 0; tid 0 (wave 0) publishes
  if (tid == 0) { fst(flg, CH1, b, 1); fst(flg, CH2, b, 1); }

  for (int t = 0; t <= NSTEP; ++t) {
    if (t < NSTEP) {
      // ======== A1: q + gh1 + gh2 (reads h1/h2 of step t-1) ========
      if (w == 0) fpoll2x256(flg, CH1, CH2, t + 1, lane);
      __syncthreads();
      if (tid < 256 || b >= 128) {  // blocks<128 need only h1
        const float* hsrc = (tid < 256) ? (p.ws + H1FO + 4 * tid)
                                        : (p.ws + H2FO + 4 * (tid - 256));
        float4 hv = cld16(hsrc);
        *(float4*)&sx[6144 + 4 * tid] = hv;
      }
      __syncthreads();
      if (b >= 128) {
        const int widx = gw - 1024;
        // q first (critical path head)
        float sq = dotchunk(wa + 32, sx + 7168, lane) + dotchunk(wa + 36, sx + 7680, lane);
        sq = wsum(sq);
        if (lane == 0) ast(p.ws + QF + widx, sq);
        VDRAIN();
        __syncthreads();
        if (tid == 0) fst(flg, CQ, b, t + 1);
        float s = dotchunk(wa + 0, sx + 6144, lane) + dotchunk(wa + 4, sx + 6656, lane);
        s = wsum(s);
        if (lane == 0) ast(p.ws + GH1F + widx * 4 + 2, s + p.bhh1[2048 + widx]);
#pragma unroll
        for (int r = 0; r < 3; ++r) {
          float t2 = dotchunk(wa + 8 + 8 * r, sx + 7168, lane) +
                     dotchunk(wa + 12 + 8 * r, sx + 7680, lane);
          t2 = wsum(t2);
          if (lane == 0) ast(p.ws + GH2F + widx * 4 + r, t2 + p.bhh2[widx + 1024 * r]);
        }
        VDRAIN();
        __syncthreads();
        if (tid == 0) fst(flg, CGH, b, t + 1);
      } else {
        float s1 = dotchunk(wa + 28, sx + 6144, lane) + dotchunk(wa + 32, sx + 6656, lane);
        s1 = wsum(s1);
        if (lane == 0) ast(p.ws + GH1F + gw * 4 + 0, s1 + p.bhh1[gw]);
        float s2 = dotchunk(wa + 36, sx + 6144, lane) + dotchunk(wa + 40, sx + 6656, lane);
        s2 = wsum(s2);
        if (lane == 0) ast(p.ws + GH1F + gw * 4 + 1, s2 + p.bhh1[1024 + gw]);
        VDRAIN();
        __syncthreads();
        if (tid == 0) fst(flg, CGH, b, t + 1);
      }

      // ======== C1: e[b] = v . tanh(pk + q) ========
      if (w == 0) fpoll128hi(flg, CQ, t + 1, lane);
      __syncthreads();
      if (tid < 256) {
        float4 qv = cld16(p.ws + QF + 4 * tid);
        float acc = va4.x * tanhf(pk4.x + qv.x) + va4.y * tanhf(pk4.y + qv.y) +
                    va4.z * tanhf(pk4.z + qv.z) + va4.w * tanhf(pk4.w + qv.w);
        acc = wsum(acc);
        if (lane == 0) s_red[w] = acc;
      }
      __syncthreads();
      if (tid == 0) {
        float e = s_red[0] + s_red[1] + s_red[2] + s_red[3];
        ast(p.ws + EF + b, e);
        VDRAIN();
        fst(flg, CE, b, t + 1);
      }
    }

    // ======== A2: epilogue(t-1) pre + out (overlaps others' C1/C2) ====
    // Reuses emb(t-1) @ sx[0:512) and ctx(t-1) @ sx[512:2560) staged by D(t-1).
    if (t > 0) {
      if (t == NSTEP) {
        if (w == 0) fpoll256(flg, CH2, t + 1, lane);
      }
      __syncthreads();
      if (tid < 256) {
        float4 v = cld16(p.ws + O2F + 4 * tid);
        *(float4*)&sx[2560 + 4 * tid] = v;
      }
      __syncthreads();
      if (gw < 1024) {
        float s = 0.f;
#pragma unroll
        for (int c = 0; c < 7; ++c) {
          const float* xp = (c == 0) ? sx
                          : (c <= 2) ? (sx + 2560 + (c - 1) * 512)
                                     : (sx + 512 + (c - 3) * 512);
          s += dotchunk(wa + 4 * c, xp, lane);
        }
        s = wsum(s);
        if (lane == 0) pres[(size_t)(t - 1) * 1024 + gw] = lrelu(s + p.bpre[gw]);
      } else if (gw - 1024 < 512) {
        const int widx = gw - 1024;
        float so = dotchunk(wa + 40, sx + 2560, lane) + dotchunk(wa + 44, sx + 3072, lane);
        so = wsum(so);
        if (lane == 0) outs[(size_t)(t - 1) * 512 + widx] = so + p.bout[widx];
      }
    }
    if (t == NSTEP) break;

    // ======== C2: softmax over e + ctx columns ========
    {
      if (w == 0) fpoll256(flg, CE, t + 1, lane);
      __syncthreads();
      if (tid < 64) {
        float4 ev = cld16(p.ws + EF + 4 * tid);
        *(float4*)&sx[4096 + 4 * tid] = ev;
      }
      __syncthreads();
      float e_i = 0.f, pe = 0.f;
      if (tid < 256) {
        e_i = sx[4096 + tid];
        float mw = e_i;
#pragma unroll
        for (int o = 32; o; o >>= 1) mw = fmaxf(mw, __shfl_xor(mw, o, 64));
        if (lane == 0) s_red[w] = mw;
      }
      __syncthreads();
      float m = fmaxf(fmaxf(s_red[0], s_red[1]), fmaxf(s_red[2], s_red[3]));
      __syncthreads();
      if (tid < 256) {
        pe = expf(e_i - m);
        float zw = wsum(pe);
        if (lane == 0) s_red[w] = zw;
      }
      __syncthreads();
      float Z = s_red[0] + s_red[1] + s_red[2] + s_red[3];
      if (tid < 256) {
        float alpha = pe / Z;
        if (b == 0) alph[(size_t)t * 256 + tid] = alpha;
        float c[8];
        c[0] = alpha * blo(wenc[0]); c[1] = alpha * bhi(wenc[0]);
        c[2] = alpha * blo(wenc[1]); c[3] = alpha * bhi(wenc[1]);
        c[4] = alpha * blo(wenc[2]); c[5] = alpha * bhi(wenc[2]);
        c[6] = alpha * blo(wenc[3]); c[7] = alpha * bhi(wenc[3]);
#pragma unroll
        for (int o = 32; o; o >>= 1) {
#pragma unroll
          for (int j = 0; j < 8; ++j) c[j] += __shfl_xor(c[j], o, 64);
        }
        if (lane == 0) {
#pragma unroll
          for (int j = 0; j < 8; ++j) s_part[w * 8 + j] = c[j];
        }
      }
      __syncthreads();
      if (tid < 8) {
        float cj = s_part[tid] + s_part[8 + tid] + s_part[16 + tid] + s_part[24 + tid];
        ast(p.ws + CTXF + j0 + tid, cj);
      }
      VDRAIN();  // ctx stores are wave 0; tid0 publishes
      if (tid == 0) fst(flg, CCTX, b, t + 1);
    }

    // ======== D: GRU1; x=[emb(t)|ctx(t)] @ sx[0:2560) ========
    {
      if (w == 0) {
        fpoll256(flg, CCTX, t + 1, lane);
        fpollp2(flg, CGH, b >> 1, 128 + (b >> 1), t + 1);  // point-to-point gh dep
      }
      __syncthreads();
      const float* embc = p.embeds + (size_t)p.inputs[t] * 512;
      sx[tid] = embc[tid];
      {
        float4 cv = cld16(p.ws + CTXF + 4 * tid);
        *(float4*)&sx[512 + 4 * tid] = cv;
      }
      float4 g1 = {0.f, 0.f, 0.f, 0.f};
      float h1old = 0.f;
      if (tid < 4) {
        g1 = cld16(p.ws + GH1F + (i0 + tid) * 4);
        h1old = ald(p.ws + H1FO + i0 + tid);
      }
      __syncthreads();
#pragma unroll
      for (int k = 0; k < 8; ++k) {
        const int mm = w + 8 * k;
        if (mm < 60) {  // wave-uniform
          const int c = (mm % 15) % 5;
          float s = dotchunk(wd + 4 * k, sx + c * 512, lane);
          s = wsum(s);
          if (lane == 0) s_part[mm] = s;
        }
      }
      __syncthreads();
      if (tid < 4) {
        const int i = i0 + tid;
        const float* sp = s_part + tid * 15;
        float sr = sp[0] + sp[1] + sp[2] + sp[3] + sp[4];
        float sz = sp[5] + sp[6] + sp[7] + sp[8] + sp[9];
        float sn = sp[10] + sp[11] + sp[12] + sp[13] + sp[14];
        float r = sigm(sr + p.bih1[i] + g1.x);
        float z = sigm(sz + p.bih1[1024 + i] + g1.y);
        float n = tanhf(sn + p.bih1[2048 + i] + r * g1.z);
        float h = (1.f - z) * n + z * h1old;
        ast(p.ws + H1FO + i, h);
        ast(p.ws + O1F + i, lrelu(h));
      }
      VDRAIN();  // stores are wave 0
      if (tid == 0) fst(flg, CH1, b, t + 2);
    }

    // ======== E: GRU2; x = [o1 @ sx[2560:3584) | ctx @ sx[512:2560)] ========
    {
      if (w == 0) fpoll256(flg, CH1, t + 2, lane);
      __syncthreads();
      if (tid < 256) {
        float4 ov = cld16(p.ws + O1F + 4 * tid);
        *(float4*)&sx[2560 + 4 * tid] = ov;
      }
      float4 g2 = {0.f, 0.f, 0.f, 0.f};
      float h2old = 0.f;
      if (tid < 4) {
        g2 = cld16(p.ws + GH2F + (i0 + tid) * 4);
        h2old = ald(p.ws + H2FO + i0 + tid);
      }
      __syncthreads();
#pragma unroll
      for (int k = 0; k < 9; ++k) {
        const int mm = w + 8 * k;  // < 72 always
        const int c = (mm % 18) % 6;
        const float* xp = (c < 2) ? (sx + 2560 + c * 512) : (sx + 512 + (c - 2) * 512);
        float s = dotchunk(we9 + 4 * k, xp, lane);
        s = wsum(s);
        if (lane == 0) s_part[mm] = s;
      }
      __syncthreads();
      if (tid < 4) {
        const int i = i0 + tid;
        const float* sp = s_part + tid * 18;
        float sr = sp[0] + sp[1] + sp[2] + sp[3] + sp[4] + sp[5];
        float sz = sp[6] + sp[7] + sp[8] + sp[9] + sp[10] + sp[11];
        float sn = sp[12] + sp[13] + sp[14] + sp[15] + sp[16] + sp[17];
        float r = sigm(sr + p.bih2[i] + g2.x);
        float z = sigm(sz + p.bih2[1024 + i] + g2.y);
        float n = tanhf(sn + p.bih2[2048 + i] + r * g2.z);
        float h = (1.f - z) * n + z * h2old;
        ast(p.ws + H2FO + i, h);
        ast(p.ws + O2F + i, lrelu(h));
      }
      VDRAIN();  // stores are wave 0
      if (tid == 0) fst(flg, CH2, b, t + 2);
    }
  }

  // ======== Final state outputs: block writes its own rows ========
  if (tid < 4) {
    h1f[i0 + tid] = ald(p.ws + H1FO + i0 + tid);
    h2f[i0 + tid] = ald(p.ws + H2FO + i0 + tid);
  }
}

extern "C" void kernel_launch(void* const* d_in, const int* in_sizes, int n_in,
                              void* d_out, int out_size, void* d_ws, size_t ws_size,
                              hipStream_t stream) {
  (void)hipMemsetAsync(d_ws, 0, 8192, stream);  // zero flag words

  Params p;
  p.inputs = (const int*)d_in[0];
  p.h1_in = (const float*)d_in[1];
  p.h2_in = (const float*)d_in[2];
  p.pk = (const float*)d_in[3];
  p.enc = (const float*)d_in[4];
  p.embeds = (const float*)d_in[5];
  p.Wq = (const float*)d_in[6];
  p.vatt = (const float*)d_in[7];
  p.Wih1 = (const float*)d_in[8];
  p.Whh1 = (const float*)d_in[9];
  p.bih1 = (const float*)d_in[10];
  p.bhh1 = (const float*)d_in[11];
  p.Wih2 = (const float*)d_in[12];
  p.Whh2 = (const float*)d_in[13];
  p.bih2 = (const float*)d_in[14];
  p.bhh2 = (const float*)d_in[15];
  p.Wpre = (const float*)d_in[16];
  p.bpre = (const float*)d_in[17];
  p.Wout = (const float*)d_in[18];
  p.bout = (const float*)d_in[19];
  p.out = (float*)d_out;
  p.ws = (float*)d_ws;

  void* args[] = {&p};
  hipError_t err = hipLaunchCooperativeKernel((const void*)dec_flag_kernel,
                                              dim3(GBLK), dim3(BT), args, 0, stream);
  if (err != hipSuccess) {
    // Fallback: plain launch. 256 blocks at 1 block/CU are trivially co-resident,
    // so the dataflow polling remains safe.
    dec_flag_kernel<<<dim3(GBLK), dim3(BT), 0, stream>>>(p);
  }
}